// Round 12
// baseline (175.353 us; speedup 1.0000x reference)
//
#include <hip/hip_runtime.h>
#include <math.h>

// Problem constants (fixed by the reference)
constexpr int B = 16384;
constexpr int D = 128;   // state dim
constexpr int H = 128;   // hidden
constexpr int O = 32;    // options
constexpr int A = 64;    // actions

constexpr int NB1 = 32;  // samples per block, phase 1
constexpr int NT1 = 256;
constexpr int NBLK1 = B / NB1;        // 512 option blocks + 512 term blocks
constexpr int TS    = 32;   // samples per tile, phase 2
constexpr int NT2   = 256;
constexpr int SLOTS = 32;   // tile slots per option -> grid 32*32 = 1024

// ws layout: counts int[32] (zeroed via hipMemsetAsync) | bucket int[32*B] (2 MB)

// Phase 1: option head and termination head in SEPARATE blocks
// (r11-verified numerics; selection threads now also scatter into per-option
//  bucket regions via device-scope atomics — replaces the mid kernel.)
__global__ __launch_bounds__(NT1) void phase1(
    const float* __restrict__ state, const float* __restrict__ u,
    const float* __restrict__ opt_w1, const float* __restrict__ opt_b1,
    const float* __restrict__ opt_w2, const float* __restrict__ opt_b2,
    const float* __restrict__ term_w1, const float* __restrict__ term_b1,
    const float* __restrict__ term_w2, const float* __restrict__ term_b2,
    float* __restrict__ out_optp, float* __restrict__ out_term,
    float* __restrict__ out_selopt,
    int* __restrict__ counts, int* __restrict__ bucket)
{
    __shared__ float s_x[NB1][D];      // 16 KB; option path reuses as hidden h
    __shared__ float s_probs[NB1][O];  // 4 KB (option path only)
    __shared__ float s_term[NB1];      // (term path only)

    const int tid   = threadIdx.x;
    const bool isOpt = blockIdx.x < (unsigned)NBLK1;
    const int b0    = (blockIdx.x & (NBLK1 - 1)) * NB1;

    // stage 32 state rows: 1024 float4 / 256 threads = 4 each
    #pragma unroll
    for (int i = 0; i < 4; ++i) {
        const int lin = tid + i * NT1;
        const int row = lin >> 5, col = (lin & 31) << 2;
        *(float4*)&s_x[row][col] =
            *(const float4*)&state[(size_t)(b0 + row) * D + col];
    }
    __syncthreads();

    const int q  = tid & 31;   // neuron quad: neurons n4..n4+3
    const int n4 = q << 2;
    const int g  = tid >> 5;   // 8 sample groups x 4 samples
    const int s0 = g << 2;

    if (isOpt) {
        // ---------------- option head ----------------
        float4 accO[4];
        {
            const float4 bO = *(const float4*)&opt_b1[n4];
            #pragma unroll
            for (int j = 0; j < 4; ++j) accO[j] = bO;
        }
        #pragma unroll 4
        for (int d = 0; d < D; d += 4) {
            float4 wO[4];
            #pragma unroll
            for (int i = 0; i < 4; ++i)
                wO[i] = *(const float4*)&opt_w1[(d + i) * H + n4];
            #pragma unroll
            for (int j = 0; j < 4; ++j) {
                const float4 x = *(const float4*)&s_x[s0 + j][d];
                const float xs[4] = {x.x, x.y, x.z, x.w};
                #pragma unroll
                for (int i = 0; i < 4; ++i) {
                    accO[j].x = fmaf(xs[i], wO[i].x, accO[j].x);
                    accO[j].y = fmaf(xs[i], wO[i].y, accO[j].y);
                    accO[j].z = fmaf(xs[i], wO[i].z, accO[j].z);
                    accO[j].w = fmaf(xs[i], wO[i].w, accO[j].w);
                }
            }
        }
        __syncthreads();            // all s_x(state) reads done
        #pragma unroll
        for (int j = 0; j < 4; ++j) {
            float4 h;
            h.x = fmaxf(accO[j].x, 0.f); h.y = fmaxf(accO[j].y, 0.f);
            h.z = fmaxf(accO[j].z, 0.f); h.w = fmaxf(accO[j].w, 0.f);
            *(float4*)&s_x[s0 + j][n4] = h;
        }
        __syncthreads();

        // option logits + softmax: o = tid&31, 4 samples per thread
        {
            const int o  = tid & 31;
            const int t0 = (tid >> 5) << 2;
            float acc4[4];
            {
                const float bb = opt_b2[o];
                #pragma unroll
                for (int j = 0; j < 4; ++j) acc4[j] = bb;
            }
            for (int h = 0; h < H; h += 4) {
                const float w0 = opt_w2[(h + 0) * O + o];
                const float w1 = opt_w2[(h + 1) * O + o];
                const float w2 = opt_w2[(h + 2) * O + o];
                const float w3 = opt_w2[(h + 3) * O + o];
                #pragma unroll
                for (int j = 0; j < 4; ++j) {
                    const float4 hv = *(const float4*)&s_x[t0 + j][h];
                    acc4[j] = fmaf(hv.x, w0, acc4[j]);
                    acc4[j] = fmaf(hv.y, w1, acc4[j]);
                    acc4[j] = fmaf(hv.z, w2, acc4[j]);
                    acc4[j] = fmaf(hv.w, w3, acc4[j]);
                }
            }
            #pragma unroll
            for (int j = 0; j < 4; ++j) {
                const float v = acc4[j];
                float m = v;
                #pragma unroll
                for (int mask = 16; mask; mask >>= 1)
                    m = fmaxf(m, __shfl_xor(m, mask, 32));
                const float e = expf(v - m);
                float ss = e;
                #pragma unroll
                for (int mask = 16; mask; mask >>= 1)
                    ss += __shfl_xor(ss, mask, 32);
                const float p = e / ss;
                s_probs[t0 + j][o] = p;
                out_optp[(size_t)(b0 + t0 + j) * O + o] = p;
            }
        }
        __syncthreads();

        // selection (exact sequential cumsum) + atomic scatter into bucket
        if (tid < NB1) {
            const float uu = u[b0 + tid];
            float c = 0.f; int cnt = 0;
            for (int o = 0; o < O; ++o) {
                c += s_probs[tid][o];
                cnt += (c < uu) ? 1 : 0;
            }
            const int sel = (cnt < O - 1) ? cnt : (O - 1);
            out_selopt[b0 + tid] = (float)sel;
            const int pos = atomicAdd(&counts[sel], 1);
            bucket[sel * B + pos] = b0 + tid;
        }
    } else {
        // ---------------- termination head ----------------
        float4 accT[4];
        {
            const float4 bT = *(const float4*)&term_b1[n4];
            #pragma unroll
            for (int j = 0; j < 4; ++j) accT[j] = bT;
        }
        #pragma unroll 4
        for (int d = 0; d < D; d += 4) {
            float4 wT[4];
            #pragma unroll
            for (int i = 0; i < 4; ++i)
                wT[i] = *(const float4*)&term_w1[(d + i) * H + n4];
            #pragma unroll
            for (int j = 0; j < 4; ++j) {
                const float4 x = *(const float4*)&s_x[s0 + j][d];
                const float xs[4] = {x.x, x.y, x.z, x.w};
                #pragma unroll
                for (int i = 0; i < 4; ++i) {
                    accT[j].x = fmaf(xs[i], wT[i].x, accT[j].x);
                    accT[j].y = fmaf(xs[i], wT[i].y, accT[j].y);
                    accT[j].z = fmaf(xs[i], wT[i].z, accT[j].z);
                    accT[j].w = fmaf(xs[i], wT[i].w, accT[j].w);
                }
            }
        }
        const float4 w2v = *(const float4*)&term_w2[n4];
        #pragma unroll
        for (int j = 0; j < 4; ++j) {
            float t = fmaxf(accT[j].x, 0.f) * w2v.x + fmaxf(accT[j].y, 0.f) * w2v.y
                    + fmaxf(accT[j].z, 0.f) * w2v.z + fmaxf(accT[j].w, 0.f) * w2v.w;
            #pragma unroll
            for (int mask = 16; mask; mask >>= 1)
                t += __shfl_xor(t, mask, 32);
            if (q == 0) s_term[s0 + j] = t;
        }
        __syncthreads();
        if (tid < NB1) {
            const float x = s_term[tid] + term_b2[0];
            out_term[b0 + tid] = 1.f / (1.f + expf(-x));
        }
    }
}

// Phase 2: routed expert MLP from per-option bucket regions. TS=32, SLOTS=32.
// Hidden K-loop unroll 8 (32 weight loads in flight / group); logits unroll 4.
__global__ __launch_bounds__(NT2) void phase2(
    const float* __restrict__ state,
    const float* __restrict__ exp_w1, const float* __restrict__ exp_b1,
    const float* __restrict__ exp_w2, const float* __restrict__ exp_b2,
    float* __restrict__ out_actp, float* __restrict__ out_selact,
    const int* __restrict__ counts, const int* __restrict__ bucket)
{
    __shared__ float s_x2[TS][D + 4];   // 16.5 KB padded; reused as hidden h
    __shared__ int   s_idx[TS];

    const int slot = blockIdx.x;
    const int o    = blockIdx.y;
    const int cnt  = counts[o];
    const int off  = o * B;
    const int tid  = threadIdx.x;
    const float* w1p = exp_w1 + (size_t)o * D * H;
    const float* w2p = exp_w2 + (size_t)o * H * A;

    const int q  = tid & 31, n4 = q << 2;
    const int g2 = tid >> 5, s02 = g2 << 2;          // 8 groups x 4 samples
    const int a4 = (tid & 15) << 2, tg = tid >> 4;   // 16 groups x 2 samples

    for (int t = slot; t * TS < cnt; t += SLOTS) {
        const int start = t * TS;
        const int nloc  = min(TS, cnt - start);

        __syncthreads();   // guard s_idx/s_x2 reuse from previous tile
        if (tid < TS) s_idx[tid] = (tid < nloc) ? bucket[off + start + tid] : 0;
        __syncthreads();

        // gather 32 state rows: 1024 float4 / 256 threads = 4 each
        #pragma unroll
        for (int i = 0; i < 4; ++i) {
            const int lin = tid + i * NT2;
            const int row = lin >> 5, col = (lin & 31) << 2;
            float4 v = make_float4(0.f, 0.f, 0.f, 0.f);
            if (row < nloc)
                v = *(const float4*)&state[(size_t)s_idx[row] * D + col];
            *(float4*)&s_x2[row][col] = v;
        }
        __syncthreads();

        // hidden: 4 neurons x 4 samples per thread
        float4 acc[4];
        {
            const float4 bia = *(const float4*)&exp_b1[o * H + n4];
            #pragma unroll
            for (int j = 0; j < 4; ++j) acc[j] = bia;
        }
        #pragma unroll 8
        for (int d = 0; d < D; d += 4) {
            float4 w[4];
            #pragma unroll
            for (int i = 0; i < 4; ++i)
                w[i] = *(const float4*)&w1p[(d + i) * H + n4];
            #pragma unroll
            for (int j = 0; j < 4; ++j) {
                const float4 x = *(const float4*)&s_x2[s02 + j][d];
                const float xs[4] = {x.x, x.y, x.z, x.w};
                #pragma unroll
                for (int i = 0; i < 4; ++i) {
                    acc[j].x = fmaf(xs[i], w[i].x, acc[j].x);
                    acc[j].y = fmaf(xs[i], w[i].y, acc[j].y);
                    acc[j].z = fmaf(xs[i], w[i].z, acc[j].z);
                    acc[j].w = fmaf(xs[i], w[i].w, acc[j].w);
                }
            }
        }
        __syncthreads();
        #pragma unroll
        for (int j = 0; j < 4; ++j) {
            float4 h;
            h.x = fmaxf(acc[j].x, 0.f); h.y = fmaxf(acc[j].y, 0.f);
            h.z = fmaxf(acc[j].z, 0.f); h.w = fmaxf(acc[j].w, 0.f);
            *(float4*)&s_x2[s02 + j][n4] = h;
        }
        __syncthreads();

        // logits: 4 actions x 2 samples per thread
        float4 la[2];
        la[0] = make_float4(0.f, 0.f, 0.f, 0.f);
        la[1] = la[0];
        #pragma unroll 4
        for (int h = 0; h < H; h += 4) {
            float4 w[4];
            #pragma unroll
            for (int i = 0; i < 4; ++i)
                w[i] = *(const float4*)&w2p[(h + i) * A + a4];
            #pragma unroll
            for (int j = 0; j < 2; ++j) {
                const float4 x = *(const float4*)&s_x2[tg * 2 + j][h];
                const float xs[4] = {x.x, x.y, x.z, x.w};
                #pragma unroll
                for (int i = 0; i < 4; ++i) {
                    la[j].x = fmaf(xs[i], w[i].x, la[j].x);
                    la[j].y = fmaf(xs[i], w[i].y, la[j].y);
                    la[j].z = fmaf(xs[i], w[i].z, la[j].z);
                    la[j].w = fmaf(xs[i], w[i].w, la[j].w);
                }
            }
        }
        const float4 bias2 = *(const float4*)&exp_b2[o * A + a4];

        #pragma unroll
        for (int j = 0; j < 2; ++j) {
            const int srow = tg * 2 + j;
            float4 v;
            v.x = la[j].x + bias2.x; v.y = la[j].y + bias2.y;
            v.z = la[j].z + bias2.z; v.w = la[j].w + bias2.w;
            float m = fmaxf(fmaxf(v.x, v.y), fmaxf(v.z, v.w));
            #pragma unroll
            for (int mask = 8; mask; mask >>= 1)
                m = fmaxf(m, __shfl_xor(m, mask, 16));
            float4 e;
            e.x = expf(v.x - m); e.y = expf(v.y - m);
            e.z = expf(v.z - m); e.w = expf(v.w - m);
            float ss = e.x + e.y + e.z + e.w;
            #pragma unroll
            for (int mask = 8; mask; mask >>= 1)
                ss += __shfl_xor(ss, mask, 16);
            const float inv = 1.f / ss;
            float4 p;
            p.x = e.x * inv; p.y = e.y * inv; p.z = e.z * inv; p.w = e.w * inv;
            // argmax on probs, first-index tiebreak
            float bv = p.x; int bi = a4;
            if (p.y > bv) { bv = p.y; bi = a4 + 1; }
            if (p.z > bv) { bv = p.z; bi = a4 + 2; }
            if (p.w > bv) { bv = p.w; bi = a4 + 3; }
            #pragma unroll
            for (int mask = 8; mask; mask >>= 1) {
                const float ov = __shfl_xor(bv, mask, 16);
                const int   oi = __shfl_xor(bi, mask, 16);
                if (ov > bv || (ov == bv && oi < bi)) { bv = ov; bi = oi; }
            }
            if (srow < nloc) {
                const int gidx = s_idx[srow];
                *(float4*)&out_actp[(size_t)gidx * A + a4] = p;
                if ((tid & 15) == 0) out_selact[gidx] = (float)bi;
            }
        }
    }
}

extern "C" void kernel_launch(void* const* d_in, const int* in_sizes, int n_in,
                              void* d_out, int out_size, void* d_ws, size_t ws_size,
                              hipStream_t stream) {
    const float* state   = (const float*)d_in[0];
    const float* u       = (const float*)d_in[1];
    const float* opt_w1  = (const float*)d_in[2];
    const float* opt_b1  = (const float*)d_in[3];
    const float* opt_w2  = (const float*)d_in[4];
    const float* opt_b2  = (const float*)d_in[5];
    const float* exp_w1  = (const float*)d_in[6];
    const float* exp_b1  = (const float*)d_in[7];
    const float* exp_w2  = (const float*)d_in[8];
    const float* exp_b2  = (const float*)d_in[9];
    const float* term_w1 = (const float*)d_in[10];
    const float* term_b1 = (const float*)d_in[11];
    const float* term_w2 = (const float*)d_in[12];
    const float* term_b2 = (const float*)d_in[13];

    float* out = (float*)d_out;
    float* out_optp   = out;                        // [B, O]
    float* out_actp   = out_optp + (size_t)B * O;   // [B, A]
    float* out_term   = out_actp + (size_t)B * A;   // [B, 1]
    float* out_selopt = out_term + B;               // [B]
    float* out_selact = out_selopt + B;             // [B]

    int* wsi    = (int*)d_ws;
    int* counts = wsi;            // 32 ints
    int* bucket = wsi + 32;       // 32 * B ints (2 MB)

    hipMemsetAsync(counts, 0, O * sizeof(int), stream);
    hipLaunchKernelGGL(phase1, dim3(2 * NBLK1), dim3(NT1), 0, stream,
                       state, u, opt_w1, opt_b1, opt_w2, opt_b2,
                       term_w1, term_b1, term_w2, term_b2,
                       out_optp, out_term, out_selopt, counts, bucket);
    hipLaunchKernelGGL(phase2, dim3(SLOTS, O), dim3(NT2), 0, stream,
                       state, exp_w1, exp_b1, exp_w2, exp_b2,
                       out_actp, out_selact, counts, bucket);
}

// Round 13
// 149.066 us; speedup vs baseline: 1.1763x; 1.1763x over previous
//
#include <hip/hip_runtime.h>
#include <math.h>

// Problem constants (fixed by the reference)
constexpr int B = 16384;
constexpr int D = 128;   // state dim
constexpr int H = 128;   // hidden
constexpr int O = 32;    // options
constexpr int A = 64;    // actions

constexpr int NB1 = 32;  // samples per block, phase 1
constexpr int NT1 = 256;
constexpr int NBLK1 = B / NB1;        // 512 option blocks + 512 term blocks
constexpr int TS    = 32;   // samples per tile, phase 2
constexpr int NT2   = 256;
constexpr int SLOTS = 32;   // tile slots per option -> grid 32*32 = 1024

// ws layout: sel int[B] (64KB) | bucket u16[B] (32KB) | counts[32] | offsets[32]

// Phase 1: option head and termination head in SEPARATE blocks
// (verified passing in rounds 8 and 11 — unchanged)
__global__ __launch_bounds__(NT1) void phase1(
    const float* __restrict__ state, const float* __restrict__ u,
    const float* __restrict__ opt_w1, const float* __restrict__ opt_b1,
    const float* __restrict__ opt_w2, const float* __restrict__ opt_b2,
    const float* __restrict__ term_w1, const float* __restrict__ term_b1,
    const float* __restrict__ term_w2, const float* __restrict__ term_b2,
    float* __restrict__ out_optp, float* __restrict__ out_term,
    float* __restrict__ out_selopt, int* __restrict__ ws_sel)
{
    __shared__ float s_x[NB1][D];      // 16 KB; option path reuses as hidden h
    __shared__ float s_probs[NB1][O];  // 4 KB (option path only)
    __shared__ float s_term[NB1];      // (term path only)

    const int tid   = threadIdx.x;
    const bool isOpt = blockIdx.x < (unsigned)NBLK1;
    const int b0    = (blockIdx.x & (NBLK1 - 1)) * NB1;

    // stage 32 state rows: 1024 float4 / 256 threads = 4 each
    #pragma unroll
    for (int i = 0; i < 4; ++i) {
        const int lin = tid + i * NT1;
        const int row = lin >> 5, col = (lin & 31) << 2;
        *(float4*)&s_x[row][col] =
            *(const float4*)&state[(size_t)(b0 + row) * D + col];
    }
    __syncthreads();

    const int q  = tid & 31;   // neuron quad: neurons n4..n4+3
    const int n4 = q << 2;
    const int g  = tid >> 5;   // 8 sample groups x 4 samples
    const int s0 = g << 2;

    if (isOpt) {
        // ---------------- option head ----------------
        float4 accO[4];
        {
            const float4 bO = *(const float4*)&opt_b1[n4];
            #pragma unroll
            for (int j = 0; j < 4; ++j) accO[j] = bO;
        }
        #pragma unroll 4
        for (int d = 0; d < D; d += 4) {
            float4 wO[4];
            #pragma unroll
            for (int i = 0; i < 4; ++i)
                wO[i] = *(const float4*)&opt_w1[(d + i) * H + n4];
            #pragma unroll
            for (int j = 0; j < 4; ++j) {
                const float4 x = *(const float4*)&s_x[s0 + j][d];
                const float xs[4] = {x.x, x.y, x.z, x.w};
                #pragma unroll
                for (int i = 0; i < 4; ++i) {
                    accO[j].x = fmaf(xs[i], wO[i].x, accO[j].x);
                    accO[j].y = fmaf(xs[i], wO[i].y, accO[j].y);
                    accO[j].z = fmaf(xs[i], wO[i].z, accO[j].z);
                    accO[j].w = fmaf(xs[i], wO[i].w, accO[j].w);
                }
            }
        }
        __syncthreads();            // all s_x(state) reads done
        #pragma unroll
        for (int j = 0; j < 4; ++j) {
            float4 h;
            h.x = fmaxf(accO[j].x, 0.f); h.y = fmaxf(accO[j].y, 0.f);
            h.z = fmaxf(accO[j].z, 0.f); h.w = fmaxf(accO[j].w, 0.f);
            *(float4*)&s_x[s0 + j][n4] = h;
        }
        __syncthreads();

        // option logits + softmax: o = tid&31, 4 samples per thread
        {
            const int o  = tid & 31;
            const int t0 = (tid >> 5) << 2;
            float acc4[4];
            {
                const float bb = opt_b2[o];
                #pragma unroll
                for (int j = 0; j < 4; ++j) acc4[j] = bb;
            }
            for (int h = 0; h < H; h += 4) {
                const float w0 = opt_w2[(h + 0) * O + o];
                const float w1 = opt_w2[(h + 1) * O + o];
                const float w2 = opt_w2[(h + 2) * O + o];
                const float w3 = opt_w2[(h + 3) * O + o];
                #pragma unroll
                for (int j = 0; j < 4; ++j) {
                    const float4 hv = *(const float4*)&s_x[t0 + j][h];
                    acc4[j] = fmaf(hv.x, w0, acc4[j]);
                    acc4[j] = fmaf(hv.y, w1, acc4[j]);
                    acc4[j] = fmaf(hv.z, w2, acc4[j]);
                    acc4[j] = fmaf(hv.w, w3, acc4[j]);
                }
            }
            #pragma unroll
            for (int j = 0; j < 4; ++j) {
                const float v = acc4[j];
                float m = v;
                #pragma unroll
                for (int mask = 16; mask; mask >>= 1)
                    m = fmaxf(m, __shfl_xor(m, mask, 32));
                const float e = expf(v - m);
                float ss = e;
                #pragma unroll
                for (int mask = 16; mask; mask >>= 1)
                    ss += __shfl_xor(ss, mask, 32);
                const float p = e / ss;
                s_probs[t0 + j][o] = p;
                out_optp[(size_t)(b0 + t0 + j) * O + o] = p;
            }
        }
        __syncthreads();

        // selection (exact sequential cumsum)
        if (tid < NB1) {
            const float uu = u[b0 + tid];
            float c = 0.f; int cnt = 0;
            for (int o = 0; o < O; ++o) {
                c += s_probs[tid][o];
                cnt += (c < uu) ? 1 : 0;
            }
            const int sel = (cnt < O - 1) ? cnt : (O - 1);
            out_selopt[b0 + tid] = (float)sel;
            ws_sel[b0 + tid] = sel;
        }
    } else {
        // ---------------- termination head ----------------
        float4 accT[4];
        {
            const float4 bT = *(const float4*)&term_b1[n4];
            #pragma unroll
            for (int j = 0; j < 4; ++j) accT[j] = bT;
        }
        #pragma unroll 4
        for (int d = 0; d < D; d += 4) {
            float4 wT[4];
            #pragma unroll
            for (int i = 0; i < 4; ++i)
                wT[i] = *(const float4*)&term_w1[(d + i) * H + n4];
            #pragma unroll
            for (int j = 0; j < 4; ++j) {
                const float4 x = *(const float4*)&s_x[s0 + j][d];
                const float xs[4] = {x.x, x.y, x.z, x.w};
                #pragma unroll
                for (int i = 0; i < 4; ++i) {
                    accT[j].x = fmaf(xs[i], wT[i].x, accT[j].x);
                    accT[j].y = fmaf(xs[i], wT[i].y, accT[j].y);
                    accT[j].z = fmaf(xs[i], wT[i].z, accT[j].z);
                    accT[j].w = fmaf(xs[i], wT[i].w, accT[j].w);
                }
            }
        }
        const float4 w2v = *(const float4*)&term_w2[n4];
        #pragma unroll
        for (int j = 0; j < 4; ++j) {
            float t = fmaxf(accT[j].x, 0.f) * w2v.x + fmaxf(accT[j].y, 0.f) * w2v.y
                    + fmaxf(accT[j].z, 0.f) * w2v.z + fmaxf(accT[j].w, 0.f) * w2v.w;
            #pragma unroll
            for (int mask = 16; mask; mask >>= 1)
                t += __shfl_xor(t, mask, 32);
            if (q == 0) s_term[s0 + j] = t;
        }
        __syncthreads();
        if (tid < NB1) {
            const float x = s_term[tid] + term_b2[0];
            out_term[b0 + tid] = 1.f / (1.f + expf(-x));
        }
    }
}

// Atomic-free bucketing (verified passing in rounds 2, 3, 6, 8, 11 — unchanged)
__global__ __launch_bounds__(256) void mid(
    const int* __restrict__ ws_sel, unsigned short* __restrict__ bucket,
    int* __restrict__ counts, int* __restrict__ offsets)
{
    __shared__ int s_wsum[4];
    __shared__ int s_lt4[4];
    const int o    = blockIdx.x;
    const int tid  = threadIdx.x;
    const int lane = tid & 63, wv = tid >> 6;
    const int4* sp = (const int4*)ws_sel + tid * 16;   // 64 sels per thread

    int ce = 0, cl = 0;
    #pragma unroll 4
    for (int k = 0; k < 16; ++k) {
        const int4 v = sp[k];
        ce += (v.x == o) + (v.y == o) + (v.z == o) + (v.w == o);
        cl += (v.x <  o) + (v.y <  o) + (v.z <  o) + (v.w <  o);
    }
    int inc = ce;
    #pragma unroll
    for (int offd = 1; offd < 64; offd <<= 1) {
        const int t2 = __shfl_up(inc, offd, 64);
        if (lane >= offd) inc += t2;
    }
    int lt = cl;
    #pragma unroll
    for (int mask = 32; mask; mask >>= 1) lt += __shfl_xor(lt, mask, 64);
    if (lane == 63) s_wsum[wv] = inc;
    if (lane == 0)  s_lt4[wv]  = lt;
    __syncthreads();
    int wbase = 0;
    for (int w = 0; w < wv; ++w) wbase += s_wsum[w];
    const int ltotal = s_lt4[0] + s_lt4[1] + s_lt4[2] + s_lt4[3];
    int pos = ltotal + wbase + inc - ce;

    #pragma unroll 4
    for (int k = 0; k < 16; ++k) {
        const int4 v = sp[k];
        const int i0 = (tid * 16 + k) * 4;
        if (v.x == o) bucket[pos++] = (unsigned short)(i0);
        if (v.y == o) bucket[pos++] = (unsigned short)(i0 + 1);
        if (v.z == o) bucket[pos++] = (unsigned short)(i0 + 2);
        if (v.w == o) bucket[pos++] = (unsigned short)(i0 + 3);
    }
    if (tid == 255) {
        counts[o]  = wbase + inc;
        offsets[o] = ltotal;
    }
}

// Phase 2: routed expert MLP. TS=32/SLOTS=32 (r11 structure), but expert
// weights are staged through a 16 KB LDS chunk buffer: coalesced global->LDS
// (1 float4/thread per chunk, zero redundancy) replaces the 8x-redundant
// per-thread global weight loads. FMA order per accumulator unchanged.
__global__ __launch_bounds__(NT2) void phase2(
    const float* __restrict__ state,
    const float* __restrict__ exp_w1, const float* __restrict__ exp_b1,
    const float* __restrict__ exp_w2, const float* __restrict__ exp_b2,
    float* __restrict__ out_actp, float* __restrict__ out_selact,
    const int* __restrict__ counts, const int* __restrict__ offsets,
    const unsigned short* __restrict__ bucket)
{
    __shared__ float s_x2[TS][D + 4];   // 16.5 KB padded; reused as hidden h
    __shared__ float s_w[32 * 128];     // 16 KB chunk buffer (w1: 32 d-rows; w2: 64 h-rows)
    __shared__ int   s_idx[TS];

    const int slot = blockIdx.x;
    const int o    = blockIdx.y;
    const int cnt  = counts[o];
    const int off  = offsets[o];
    const int tid  = threadIdx.x;
    const float* w1p = exp_w1 + (size_t)o * D * H;
    const float* w2p = exp_w2 + (size_t)o * H * A;

    const int q  = tid & 31, n4 = q << 2;
    const int g2 = tid >> 5, s02 = g2 << 2;          // 8 groups x 4 samples
    const int a4 = (tid & 15) << 2, tg = tid >> 4;   // 16 groups x 2 samples

    for (int t = slot; t * TS < cnt; t += SLOTS) {
        const int start = t * TS;
        const int nloc  = min(TS, cnt - start);

        __syncthreads();   // guard s_idx/s_x2/s_w reuse from previous tile
        if (tid < TS) s_idx[tid] = (tid < nloc) ? (int)bucket[off + start + tid] : 0;
        __syncthreads();

        // gather 32 state rows: 1024 float4 / 256 threads = 4 each
        #pragma unroll
        for (int i = 0; i < 4; ++i) {
            const int lin = tid + i * NT2;
            const int row = lin >> 5, col = (lin & 31) << 2;
            float4 v = make_float4(0.f, 0.f, 0.f, 0.f);
            if (row < nloc)
                v = *(const float4*)&state[(size_t)s_idx[row] * D + col];
            *(float4*)&s_x2[row][col] = v;
        }

        // hidden: 4 neurons x 4 samples per thread; w1 staged in 4 chunks
        float4 acc[4];
        {
            const float4 bia = *(const float4*)&exp_b1[o * H + n4];
            #pragma unroll
            for (int j = 0; j < 4; ++j) acc[j] = bia;
        }
        for (int c = 0; c < 4; ++c) {
            __syncthreads();   // previous chunk's reads done (also covers gather)
            // stage 32 d-rows (16 KB): 1024 float4 / 256 threads = 4 each
            #pragma unroll
            for (int i = 0; i < 4; ++i) {
                const int l  = tid + i * NT2;          // float4 index
                const int dl = l >> 5, nn = (l & 31) << 2;
                *(float4*)&s_w[dl * 128 + nn] =
                    *(const float4*)&w1p[(c * 32 + dl) * H + nn];
            }
            __syncthreads();
            #pragma unroll 2
            for (int dl = 0; dl < 32; dl += 4) {
                float4 w[4];
                #pragma unroll
                for (int i = 0; i < 4; ++i)
                    w[i] = *(const float4*)&s_w[(dl + i) * 128 + n4];
                #pragma unroll
                for (int j = 0; j < 4; ++j) {
                    const float4 x = *(const float4*)&s_x2[s02 + j][c * 32 + dl];
                    const float xs[4] = {x.x, x.y, x.z, x.w};
                    #pragma unroll
                    for (int i = 0; i < 4; ++i) {
                        acc[j].x = fmaf(xs[i], w[i].x, acc[j].x);
                        acc[j].y = fmaf(xs[i], w[i].y, acc[j].y);
                        acc[j].z = fmaf(xs[i], w[i].z, acc[j].z);
                        acc[j].w = fmaf(xs[i], w[i].w, acc[j].w);
                    }
                }
            }
        }
        __syncthreads();
        #pragma unroll
        for (int j = 0; j < 4; ++j) {
            float4 h;
            h.x = fmaxf(acc[j].x, 0.f); h.y = fmaxf(acc[j].y, 0.f);
            h.z = fmaxf(acc[j].z, 0.f); h.w = fmaxf(acc[j].w, 0.f);
            *(float4*)&s_x2[s02 + j][n4] = h;
        }

        // logits: 4 actions x 2 samples per thread; w2 staged in 2 chunks
        float4 la[2];
        la[0] = make_float4(0.f, 0.f, 0.f, 0.f);
        la[1] = la[0];
        for (int c = 0; c < 2; ++c) {
            __syncthreads();   // previous reads of s_w (and h-write) done
            // stage 64 h-rows (16 KB): 1024 float4 / 256 threads = 4 each
            #pragma unroll
            for (int i = 0; i < 4; ++i) {
                const int l  = tid + i * NT2;          // float4 index
                const int hl = l >> 4, aa = (l & 15) << 2;   // row = 16 float4
                *(float4*)&s_w[hl * 64 + aa] =
                    *(const float4*)&w2p[(c * 64 + hl) * A + aa];
            }
            __syncthreads();
            #pragma unroll 2
            for (int hl = 0; hl < 64; hl += 4) {
                float4 w[4];
                #pragma unroll
                for (int i = 0; i < 4; ++i)
                    w[i] = *(const float4*)&s_w[(hl + i) * 64 + a4];
                #pragma unroll
                for (int j = 0; j < 2; ++j) {
                    const float4 x = *(const float4*)&s_x2[tg * 2 + j][c * 64 + hl];
                    const float xs[4] = {x.x, x.y, x.z, x.w};
                    #pragma unroll
                    for (int i = 0; i < 4; ++i) {
                        la[j].x = fmaf(xs[i], w[i].x, la[j].x);
                        la[j].y = fmaf(xs[i], w[i].y, la[j].y);
                        la[j].z = fmaf(xs[i], w[i].z, la[j].z);
                        la[j].w = fmaf(xs[i], w[i].w, la[j].w);
                    }
                }
            }
        }
        const float4 bias2 = *(const float4*)&exp_b2[o * A + a4];

        #pragma unroll
        for (int j = 0; j < 2; ++j) {
            const int srow = tg * 2 + j;
            float4 v;
            v.x = la[j].x + bias2.x; v.y = la[j].y + bias2.y;
            v.z = la[j].z + bias2.z; v.w = la[j].w + bias2.w;
            float m = fmaxf(fmaxf(v.x, v.y), fmaxf(v.z, v.w));
            #pragma unroll
            for (int mask = 8; mask; mask >>= 1)
                m = fmaxf(m, __shfl_xor(m, mask, 16));
            float4 e;
            e.x = expf(v.x - m); e.y = expf(v.y - m);
            e.z = expf(v.z - m); e.w = expf(v.w - m);
            float ss = e.x + e.y + e.z + e.w;
            #pragma unroll
            for (int mask = 8; mask; mask >>= 1)
                ss += __shfl_xor(ss, mask, 16);
            const float inv = 1.f / ss;
            float4 p;
            p.x = e.x * inv; p.y = e.y * inv; p.z = e.z * inv; p.w = e.w * inv;
            // argmax on probs, first-index tiebreak
            float bv = p.x; int bi = a4;
            if (p.y > bv) { bv = p.y; bi = a4 + 1; }
            if (p.z > bv) { bv = p.z; bi = a4 + 2; }
            if (p.w > bv) { bv = p.w; bi = a4 + 3; }
            #pragma unroll
            for (int mask = 8; mask; mask >>= 1) {
                const float ov = __shfl_xor(bv, mask, 16);
                const int   oi = __shfl_xor(bi, mask, 16);
                if (ov > bv || (ov == bv && oi < bi)) { bv = ov; bi = oi; }
            }
            if (srow < nloc) {
                const int gidx = s_idx[srow];
                *(float4*)&out_actp[(size_t)gidx * A + a4] = p;
                if ((tid & 15) == 0) out_selact[gidx] = (float)bi;
            }
        }
    }
}

extern "C" void kernel_launch(void* const* d_in, const int* in_sizes, int n_in,
                              void* d_out, int out_size, void* d_ws, size_t ws_size,
                              hipStream_t stream) {
    const float* state   = (const float*)d_in[0];
    const float* u       = (const float*)d_in[1];
    const float* opt_w1  = (const float*)d_in[2];
    const float* opt_b1  = (const float*)d_in[3];
    const float* opt_w2  = (const float*)d_in[4];
    const float* opt_b2  = (const float*)d_in[5];
    const float* exp_w1  = (const float*)d_in[6];
    const float* exp_b1  = (const float*)d_in[7];
    const float* exp_w2  = (const float*)d_in[8];
    const float* exp_b2  = (const float*)d_in[9];
    const float* term_w1 = (const float*)d_in[10];
    const float* term_b1 = (const float*)d_in[11];
    const float* term_w2 = (const float*)d_in[12];
    const float* term_b2 = (const float*)d_in[13];

    float* out = (float*)d_out;
    float* out_optp   = out;                        // [B, O]
    float* out_actp   = out_optp + (size_t)B * O;   // [B, A]
    float* out_term   = out_actp + (size_t)B * A;   // [B, 1]
    float* out_selopt = out_term + B;               // [B]
    float* out_selact = out_selopt + B;             // [B]

    int* wsi = (int*)d_ws;
    int* ws_sel = wsi;                                        // B ints
    unsigned short* bucket = (unsigned short*)(wsi + B);      // B u16
    int* counts  = wsi + B + B / 2;
    int* offsets = counts + 32;

    hipLaunchKernelGGL(phase1, dim3(2 * NBLK1), dim3(NT1), 0, stream,
                       state, u, opt_w1, opt_b1, opt_w2, opt_b2,
                       term_w1, term_b1, term_w2, term_b2,
                       out_optp, out_term, out_selopt, ws_sel);
    hipLaunchKernelGGL(mid, dim3(O), dim3(256), 0, stream,
                       ws_sel, bucket, counts, offsets);
    hipLaunchKernelGGL(phase2, dim3(SLOTS, O), dim3(NT2), 0, stream,
                       state, exp_w1, exp_b1, exp_w2, exp_b2,
                       out_actp, out_selact, counts, offsets, bucket);
}

// Round 14
// 145.794 us; speedup vs baseline: 1.2027x; 1.0224x over previous
//
#include <hip/hip_runtime.h>
#include <math.h>

// Problem constants (fixed by the reference)
constexpr int B = 16384;
constexpr int D = 128;   // state dim
constexpr int H = 128;   // hidden
constexpr int O = 32;    // options
constexpr int A = 64;    // actions

constexpr int NB1 = 32;  // samples per block, phase 1
constexpr int NT1 = 256;
constexpr int NBLK1 = B / NB1;        // 512 option blocks + 512 term blocks
constexpr int TS    = 32;   // samples per tile, phase 2
constexpr int NT2   = 256;
constexpr int SLOTS = 32;   // tile slots per option -> grid 32*32 = 1024

// ws layout: sel int[B] (64KB) | bucket u16[B] (32KB) | counts[32] | offsets[32]

// Phase 1: option head and termination head in SEPARATE blocks.
// r13-verified numerics + LDS weight staging (same pattern as r13 phase2):
// w1 staged in 4x16KB chunks; opt_w2 staged as one 16KB copy.
__global__ __launch_bounds__(NT1) void phase1(
    const float* __restrict__ state, const float* __restrict__ u,
    const float* __restrict__ opt_w1, const float* __restrict__ opt_b1,
    const float* __restrict__ opt_w2, const float* __restrict__ opt_b2,
    const float* __restrict__ term_w1, const float* __restrict__ term_b1,
    const float* __restrict__ term_w2, const float* __restrict__ term_b2,
    float* __restrict__ out_optp, float* __restrict__ out_term,
    float* __restrict__ out_selopt, int* __restrict__ ws_sel)
{
    __shared__ float s_x[NB1][D];      // 16 KB; option path reuses as hidden h
    __shared__ float s_w[32 * 128];    // 16 KB weight chunk buffer
    __shared__ float s_probs[NB1][O];  // 4 KB (option path only)
    __shared__ float s_term[NB1];      // (term path only)

    const int tid   = threadIdx.x;
    const bool isOpt = blockIdx.x < (unsigned)NBLK1;
    const int b0    = (blockIdx.x & (NBLK1 - 1)) * NB1;

    // stage 32 state rows: 1024 float4 / 256 threads = 4 each
    #pragma unroll
    for (int i = 0; i < 4; ++i) {
        const int lin = tid + i * NT1;
        const int row = lin >> 5, col = (lin & 31) << 2;
        *(float4*)&s_x[row][col] =
            *(const float4*)&state[(size_t)(b0 + row) * D + col];
    }

    const int q  = tid & 31;   // neuron quad: neurons n4..n4+3
    const int n4 = q << 2;
    const int g  = tid >> 5;   // 8 sample groups x 4 samples
    const int s0 = g << 2;

    if (isOpt) {
        // ---------------- option head ----------------
        float4 accO[4];
        {
            const float4 bO = *(const float4*)&opt_b1[n4];
            #pragma unroll
            for (int j = 0; j < 4; ++j) accO[j] = bO;
        }
        for (int c = 0; c < 4; ++c) {
            __syncthreads();   // previous chunk reads done (also covers s_x stage)
            #pragma unroll
            for (int i = 0; i < 4; ++i) {
                const int l  = tid + i * NT1;
                const int dl = l >> 5, nn = (l & 31) << 2;
                *(float4*)&s_w[dl * 128 + nn] =
                    *(const float4*)&opt_w1[(c * 32 + dl) * H + nn];
            }
            __syncthreads();
            #pragma unroll 2
            for (int dl = 0; dl < 32; dl += 4) {
                float4 wO[4];
                #pragma unroll
                for (int i = 0; i < 4; ++i)
                    wO[i] = *(const float4*)&s_w[(dl + i) * 128 + n4];
                #pragma unroll
                for (int j = 0; j < 4; ++j) {
                    const float4 x = *(const float4*)&s_x[s0 + j][c * 32 + dl];
                    const float xs[4] = {x.x, x.y, x.z, x.w};
                    #pragma unroll
                    for (int i = 0; i < 4; ++i) {
                        accO[j].x = fmaf(xs[i], wO[i].x, accO[j].x);
                        accO[j].y = fmaf(xs[i], wO[i].y, accO[j].y);
                        accO[j].z = fmaf(xs[i], wO[i].z, accO[j].z);
                        accO[j].w = fmaf(xs[i], wO[i].w, accO[j].w);
                    }
                }
            }
        }
        __syncthreads();            // all s_x(state) + s_w reads done
        #pragma unroll
        for (int j = 0; j < 4; ++j) {
            float4 h;
            h.x = fmaxf(accO[j].x, 0.f); h.y = fmaxf(accO[j].y, 0.f);
            h.z = fmaxf(accO[j].z, 0.f); h.w = fmaxf(accO[j].w, 0.f);
            *(float4*)&s_x[s0 + j][n4] = h;
        }
        // stage opt_w2 (16 KB contiguous) into s_w: 1024 float4 / 256 = 4 each
        #pragma unroll
        for (int i = 0; i < 4; ++i) {
            const int l = tid + i * NT1;
            *(float4*)&s_w[l * 4] = *(const float4*)&opt_w2[l * 4];
        }
        __syncthreads();

        // option logits + softmax: o = tid&31, 4 samples per thread (LDS weights)
        {
            const int o  = tid & 31;
            const int t0 = (tid >> 5) << 2;
            float acc4[4];
            {
                const float bb = opt_b2[o];
                #pragma unroll
                for (int j = 0; j < 4; ++j) acc4[j] = bb;
            }
            for (int h = 0; h < H; h += 4) {
                const float w0 = s_w[(h + 0) * O + o];
                const float w1 = s_w[(h + 1) * O + o];
                const float w2 = s_w[(h + 2) * O + o];
                const float w3 = s_w[(h + 3) * O + o];
                #pragma unroll
                for (int j = 0; j < 4; ++j) {
                    const float4 hv = *(const float4*)&s_x[t0 + j][h];
                    acc4[j] = fmaf(hv.x, w0, acc4[j]);
                    acc4[j] = fmaf(hv.y, w1, acc4[j]);
                    acc4[j] = fmaf(hv.z, w2, acc4[j]);
                    acc4[j] = fmaf(hv.w, w3, acc4[j]);
                }
            }
            #pragma unroll
            for (int j = 0; j < 4; ++j) {
                const float v = acc4[j];
                float m = v;
                #pragma unroll
                for (int mask = 16; mask; mask >>= 1)
                    m = fmaxf(m, __shfl_xor(m, mask, 32));
                const float e = expf(v - m);
                float ss = e;
                #pragma unroll
                for (int mask = 16; mask; mask >>= 1)
                    ss += __shfl_xor(ss, mask, 32);
                const float p = e / ss;
                s_probs[t0 + j][o] = p;
                out_optp[(size_t)(b0 + t0 + j) * O + o] = p;
            }
        }
        __syncthreads();

        // selection (exact sequential cumsum)
        if (tid < NB1) {
            const float uu = u[b0 + tid];
            float c = 0.f; int cnt = 0;
            for (int o = 0; o < O; ++o) {
                c += s_probs[tid][o];
                cnt += (c < uu) ? 1 : 0;
            }
            const int sel = (cnt < O - 1) ? cnt : (O - 1);
            out_selopt[b0 + tid] = (float)sel;
            ws_sel[b0 + tid] = sel;
        }
    } else {
        // ---------------- termination head ----------------
        float4 accT[4];
        {
            const float4 bT = *(const float4*)&term_b1[n4];
            #pragma unroll
            for (int j = 0; j < 4; ++j) accT[j] = bT;
        }
        for (int c = 0; c < 4; ++c) {
            __syncthreads();
            #pragma unroll
            for (int i = 0; i < 4; ++i) {
                const int l  = tid + i * NT1;
                const int dl = l >> 5, nn = (l & 31) << 2;
                *(float4*)&s_w[dl * 128 + nn] =
                    *(const float4*)&term_w1[(c * 32 + dl) * H + nn];
            }
            __syncthreads();
            #pragma unroll 2
            for (int dl = 0; dl < 32; dl += 4) {
                float4 wT[4];
                #pragma unroll
                for (int i = 0; i < 4; ++i)
                    wT[i] = *(const float4*)&s_w[(dl + i) * 128 + n4];
                #pragma unroll
                for (int j = 0; j < 4; ++j) {
                    const float4 x = *(const float4*)&s_x[s0 + j][c * 32 + dl];
                    const float xs[4] = {x.x, x.y, x.z, x.w};
                    #pragma unroll
                    for (int i = 0; i < 4; ++i) {
                        accT[j].x = fmaf(xs[i], wT[i].x, accT[j].x);
                        accT[j].y = fmaf(xs[i], wT[i].y, accT[j].y);
                        accT[j].z = fmaf(xs[i], wT[i].z, accT[j].z);
                        accT[j].w = fmaf(xs[i], wT[i].w, accT[j].w);
                    }
                }
            }
        }
        const float4 w2v = *(const float4*)&term_w2[n4];
        #pragma unroll
        for (int j = 0; j < 4; ++j) {
            float t = fmaxf(accT[j].x, 0.f) * w2v.x + fmaxf(accT[j].y, 0.f) * w2v.y
                    + fmaxf(accT[j].z, 0.f) * w2v.z + fmaxf(accT[j].w, 0.f) * w2v.w;
            #pragma unroll
            for (int mask = 16; mask; mask >>= 1)
                t += __shfl_xor(t, mask, 32);
            if (q == 0) s_term[s0 + j] = t;
        }
        __syncthreads();
        if (tid < NB1) {
            const float x = s_term[tid] + term_b2[0];
            out_term[b0 + tid] = 1.f / (1.f + expf(-x));
        }
    }
}

// Atomic-free bucketing (verified passing in rounds 2, 3, 6, 8, 11, 13 — unchanged)
__global__ __launch_bounds__(256) void mid(
    const int* __restrict__ ws_sel, unsigned short* __restrict__ bucket,
    int* __restrict__ counts, int* __restrict__ offsets)
{
    __shared__ int s_wsum[4];
    __shared__ int s_lt4[4];
    const int o    = blockIdx.x;
    const int tid  = threadIdx.x;
    const int lane = tid & 63, wv = tid >> 6;
    const int4* sp = (const int4*)ws_sel + tid * 16;   // 64 sels per thread

    int ce = 0, cl = 0;
    #pragma unroll 4
    for (int k = 0; k < 16; ++k) {
        const int4 v = sp[k];
        ce += (v.x == o) + (v.y == o) + (v.z == o) + (v.w == o);
        cl += (v.x <  o) + (v.y <  o) + (v.z <  o) + (v.w <  o);
    }
    int inc = ce;
    #pragma unroll
    for (int offd = 1; offd < 64; offd <<= 1) {
        const int t2 = __shfl_up(inc, offd, 64);
        if (lane >= offd) inc += t2;
    }
    int lt = cl;
    #pragma unroll
    for (int mask = 32; mask; mask >>= 1) lt += __shfl_xor(lt, mask, 64);
    if (lane == 63) s_wsum[wv] = inc;
    if (lane == 0)  s_lt4[wv]  = lt;
    __syncthreads();
    int wbase = 0;
    for (int w = 0; w < wv; ++w) wbase += s_wsum[w];
    const int ltotal = s_lt4[0] + s_lt4[1] + s_lt4[2] + s_lt4[3];
    int pos = ltotal + wbase + inc - ce;

    #pragma unroll 4
    for (int k = 0; k < 16; ++k) {
        const int4 v = sp[k];
        const int i0 = (tid * 16 + k) * 4;
        if (v.x == o) bucket[pos++] = (unsigned short)(i0);
        if (v.y == o) bucket[pos++] = (unsigned short)(i0 + 1);
        if (v.z == o) bucket[pos++] = (unsigned short)(i0 + 2);
        if (v.w == o) bucket[pos++] = (unsigned short)(i0 + 3);
    }
    if (tid == 255) {
        counts[o]  = wbase + inc;
        offsets[o] = ltotal;
    }
}

// Phase 2: routed expert MLP with LDS weight staging (verified in round 13 —
// unchanged).
__global__ __launch_bounds__(NT2) void phase2(
    const float* __restrict__ state,
    const float* __restrict__ exp_w1, const float* __restrict__ exp_b1,
    const float* __restrict__ exp_w2, const float* __restrict__ exp_b2,
    float* __restrict__ out_actp, float* __restrict__ out_selact,
    const int* __restrict__ counts, const int* __restrict__ offsets,
    const unsigned short* __restrict__ bucket)
{
    __shared__ float s_x2[TS][D + 4];   // 16.5 KB padded; reused as hidden h
    __shared__ float s_w[32 * 128];     // 16 KB chunk buffer
    __shared__ int   s_idx[TS];

    const int slot = blockIdx.x;
    const int o    = blockIdx.y;
    const int cnt  = counts[o];
    const int off  = offsets[o];
    const int tid  = threadIdx.x;
    const float* w1p = exp_w1 + (size_t)o * D * H;
    const float* w2p = exp_w2 + (size_t)o * H * A;

    const int q  = tid & 31, n4 = q << 2;
    const int g2 = tid >> 5, s02 = g2 << 2;          // 8 groups x 4 samples
    const int a4 = (tid & 15) << 2, tg = tid >> 4;   // 16 groups x 2 samples

    for (int t = slot; t * TS < cnt; t += SLOTS) {
        const int start = t * TS;
        const int nloc  = min(TS, cnt - start);

        __syncthreads();   // guard s_idx/s_x2/s_w reuse from previous tile
        if (tid < TS) s_idx[tid] = (tid < nloc) ? (int)bucket[off + start + tid] : 0;
        __syncthreads();

        // gather 32 state rows: 1024 float4 / 256 threads = 4 each
        #pragma unroll
        for (int i = 0; i < 4; ++i) {
            const int lin = tid + i * NT2;
            const int row = lin >> 5, col = (lin & 31) << 2;
            float4 v = make_float4(0.f, 0.f, 0.f, 0.f);
            if (row < nloc)
                v = *(const float4*)&state[(size_t)s_idx[row] * D + col];
            *(float4*)&s_x2[row][col] = v;
        }

        // hidden: 4 neurons x 4 samples per thread; w1 staged in 4 chunks
        float4 acc[4];
        {
            const float4 bia = *(const float4*)&exp_b1[o * H + n4];
            #pragma unroll
            for (int j = 0; j < 4; ++j) acc[j] = bia;
        }
        for (int c = 0; c < 4; ++c) {
            __syncthreads();   // previous chunk's reads done (also covers gather)
            #pragma unroll
            for (int i = 0; i < 4; ++i) {
                const int l  = tid + i * NT2;
                const int dl = l >> 5, nn = (l & 31) << 2;
                *(float4*)&s_w[dl * 128 + nn] =
                    *(const float4*)&w1p[(c * 32 + dl) * H + nn];
            }
            __syncthreads();
            #pragma unroll 2
            for (int dl = 0; dl < 32; dl += 4) {
                float4 w[4];
                #pragma unroll
                for (int i = 0; i < 4; ++i)
                    w[i] = *(const float4*)&s_w[(dl + i) * 128 + n4];
                #pragma unroll
                for (int j = 0; j < 4; ++j) {
                    const float4 x = *(const float4*)&s_x2[s02 + j][c * 32 + dl];
                    const float xs[4] = {x.x, x.y, x.z, x.w};
                    #pragma unroll
                    for (int i = 0; i < 4; ++i) {
                        acc[j].x = fmaf(xs[i], w[i].x, acc[j].x);
                        acc[j].y = fmaf(xs[i], w[i].y, acc[j].y);
                        acc[j].z = fmaf(xs[i], w[i].z, acc[j].z);
                        acc[j].w = fmaf(xs[i], w[i].w, acc[j].w);
                    }
                }
            }
        }
        __syncthreads();
        #pragma unroll
        for (int j = 0; j < 4; ++j) {
            float4 h;
            h.x = fmaxf(acc[j].x, 0.f); h.y = fmaxf(acc[j].y, 0.f);
            h.z = fmaxf(acc[j].z, 0.f); h.w = fmaxf(acc[j].w, 0.f);
            *(float4*)&s_x2[s02 + j][n4] = h;
        }

        // logits: 4 actions x 2 samples per thread; w2 staged in 2 chunks
        float4 la[2];
        la[0] = make_float4(0.f, 0.f, 0.f, 0.f);
        la[1] = la[0];
        for (int c = 0; c < 2; ++c) {
            __syncthreads();   // previous reads of s_w (and h-write) done
            #pragma unroll
            for (int i = 0; i < 4; ++i) {
                const int l  = tid + i * NT2;
                const int hl = l >> 4, aa = (l & 15) << 2;
                *(float4*)&s_w[hl * 64 + aa] =
                    *(const float4*)&w2p[(c * 64 + hl) * A + aa];
            }
            __syncthreads();
            #pragma unroll 2
            for (int hl = 0; hl < 64; hl += 4) {
                float4 w[4];
                #pragma unroll
                for (int i = 0; i < 4; ++i)
                    w[i] = *(const float4*)&s_w[(hl + i) * 64 + a4];
                #pragma unroll
                for (int j = 0; j < 2; ++j) {
                    const float4 x = *(const float4*)&s_x2[tg * 2 + j][c * 64 + hl];
                    const float xs[4] = {x.x, x.y, x.z, x.w};
                    #pragma unroll
                    for (int i = 0; i < 4; ++i) {
                        la[j].x = fmaf(xs[i], w[i].x, la[j].x);
                        la[j].y = fmaf(xs[i], w[i].y, la[j].y);
                        la[j].z = fmaf(xs[i], w[i].z, la[j].z);
                        la[j].w = fmaf(xs[i], w[i].w, la[j].w);
                    }
                }
            }
        }
        const float4 bias2 = *(const float4*)&exp_b2[o * A + a4];

        #pragma unroll
        for (int j = 0; j < 2; ++j) {
            const int srow = tg * 2 + j;
            float4 v;
            v.x = la[j].x + bias2.x; v.y = la[j].y + bias2.y;
            v.z = la[j].z + bias2.z; v.w = la[j].w + bias2.w;
            float m = fmaxf(fmaxf(v.x, v.y), fmaxf(v.z, v.w));
            #pragma unroll
            for (int mask = 8; mask; mask >>= 1)
                m = fmaxf(m, __shfl_xor(m, mask, 16));
            float4 e;
            e.x = expf(v.x - m); e.y = expf(v.y - m);
            e.z = expf(v.z - m); e.w = expf(v.w - m);
            float ss = e.x + e.y + e.z + e.w;
            #pragma unroll
            for (int mask = 8; mask; mask >>= 1)
                ss += __shfl_xor(ss, mask, 16);
            const float inv = 1.f / ss;
            float4 p;
            p.x = e.x * inv; p.y = e.y * inv; p.z = e.z * inv; p.w = e.w * inv;
            // argmax on probs, first-index tiebreak
            float bv = p.x; int bi = a4;
            if (p.y > bv) { bv = p.y; bi = a4 + 1; }
            if (p.z > bv) { bv = p.z; bi = a4 + 2; }
            if (p.w > bv) { bv = p.w; bi = a4 + 3; }
            #pragma unroll
            for (int mask = 8; mask; mask >>= 1) {
                const float ov = __shfl_xor(bv, mask, 16);
                const int   oi = __shfl_xor(bi, mask, 16);
                if (ov > bv || (ov == bv && oi < bi)) { bv = ov; bi = oi; }
            }
            if (srow < nloc) {
                const int gidx = s_idx[srow];
                *(float4*)&out_actp[(size_t)gidx * A + a4] = p;
                if ((tid & 15) == 0) out_selact[gidx] = (float)bi;
            }
        }
    }
}

extern "C" void kernel_launch(void* const* d_in, const int* in_sizes, int n_in,
                              void* d_out, int out_size, void* d_ws, size_t ws_size,
                              hipStream_t stream) {
    const float* state   = (const float*)d_in[0];
    const float* u       = (const float*)d_in[1];
    const float* opt_w1  = (const float*)d_in[2];
    const float* opt_b1  = (const float*)d_in[3];
    const float* opt_w2  = (const float*)d_in[4];
    const float* opt_b2  = (const float*)d_in[5];
    const float* exp_w1  = (const float*)d_in[6];
    const float* exp_b1  = (const float*)d_in[7];
    const float* exp_w2  = (const float*)d_in[8];
    const float* exp_b2  = (const float*)d_in[9];
    const float* term_w1 = (const float*)d_in[10];
    const float* term_b1 = (const float*)d_in[11];
    const float* term_w2 = (const float*)d_in[12];
    const float* term_b2 = (const float*)d_in[13];

    float* out = (float*)d_out;
    float* out_optp   = out;                        // [B, O]
    float* out_actp   = out_optp + (size_t)B * O;   // [B, A]
    float* out_term   = out_actp + (size_t)B * A;   // [B, 1]
    float* out_selopt = out_term + B;               // [B]
    float* out_selact = out_selopt + B;             // [B]

    int* wsi = (int*)d_ws;
    int* ws_sel = wsi;                                        // B ints
    unsigned short* bucket = (unsigned short*)(wsi + B);      // B u16
    int* counts  = wsi + B + B / 2;
    int* offsets = counts + 32;

    hipLaunchKernelGGL(phase1, dim3(2 * NBLK1), dim3(NT1), 0, stream,
                       state, u, opt_w1, opt_b1, opt_w2, opt_b2,
                       term_w1, term_b1, term_w2, term_b2,
                       out_optp, out_term, out_selopt, ws_sel);
    hipLaunchKernelGGL(mid, dim3(O), dim3(256), 0, stream,
                       ws_sel, bucket, counts, offsets);
    hipLaunchKernelGGL(phase2, dim3(SLOTS, O), dim3(NT2), 0, stream,
                       state, exp_w1, exp_b1, exp_w2, exp_b2,
                       out_actp, out_selact, counts, offsets, bucket);
}